// Round 4
// baseline (472.025 us; speedup 1.0000x reference)
//
#include <hip/hip_runtime.h>

typedef unsigned short u16;
typedef unsigned int   u32;
typedef __attribute__((ext_vector_type(4))) float  f32x4;
typedef __attribute__((ext_vector_type(8))) __bf16 bf16x8;

#define B_    4096
#define D_    1024
#define K_    3000
#define KP    3072
#define INV_T 10.0f
#define INV_E 20.0f

__device__ __forceinline__ u16 f2bf(float f) {  // round-to-nearest-even
    u32 u = __float_as_uint(f);
    u32 r = (u + 0x7fffu + ((u >> 16) & 1u)) >> 16;
    return (u16)r;
}
__device__ __forceinline__ void unpack8(uint4 v, float f[8]) {
    f[0] = __uint_as_float(v.x << 16); f[1] = __uint_as_float(v.x & 0xffff0000u);
    f[2] = __uint_as_float(v.y << 16); f[3] = __uint_as_float(v.y & 0xffff0000u);
    f[4] = __uint_as_float(v.z << 16); f[5] = __uint_as_float(v.z & 0xffff0000u);
    f[6] = __uint_as_float(v.w << 16); f[7] = __uint_as_float(v.w & 0xffff0000u);
}

#define GLDS(g, l) __builtin_amdgcn_global_load_lds( \
    (const __attribute__((address_space(1))) void*)(g), \
    (__attribute__((address_space(3))) void*)(l), 16, 0, 0)

// ---------------------------------------------------------------------------
// f32 -> bf16 conversion; W padded to KP rows with zeros.
// ---------------------------------------------------------------------------
__global__ __launch_bounds__(256) void convert_kernel(
    const float* __restrict__ z1, const float* __restrict__ z2,
    const float* __restrict__ W,
    u16* __restrict__ A1, u16* __restrict__ A2, u16* __restrict__ Wb)
{
    const int idx = blockIdx.x * 256 + threadIdx.x;
    const int n1 = B_ * D_ / 4;
    const int nW = KP * D_ / 4;
    ushort4 o;
    if (idx < n1) {
        float4 v = ((const float4*)z1)[idx];
        o.x = f2bf(v.x); o.y = f2bf(v.y); o.z = f2bf(v.z); o.w = f2bf(v.w);
        ((ushort4*)A1)[idx] = o;
    } else if (idx < 2 * n1) {
        const int j = idx - n1;
        float4 v = ((const float4*)z2)[j];
        o.x = f2bf(v.x); o.y = f2bf(v.y); o.z = f2bf(v.z); o.w = f2bf(v.w);
        ((ushort4*)A2)[j] = o;
    } else {
        const int j = idx - 2 * n1;
        if (j < nW) {
            const int row = j >> 8;
            if (row < K_) {
                float4 v = ((const float4*)W)[j];
                o.x = f2bf(v.x); o.y = f2bf(v.y); o.z = f2bf(v.z); o.w = f2bf(v.w);
            } else {
                o.x = 0; o.y = 0; o.z = 0; o.w = 0;
            }
            ((ushort4*)Wb)[j] = o;
        }
    }
}

// ---------------------------------------------------------------------------
// scores = z @ W^T. 128x128 tile, BK=64, 4 waves (2x2), 4x4 16x16x32 frags.
// LDS XOR-swizzle: linear global_load_lds dest, source slot pre-swizzled,
// swizzled ds_read -> 0 bank conflicts (verified round 3).
// Fused epilogue: bf16 score store, colsum0_j = sum_i e^{s/eps} (u=1 pass),
// rowT_i = sum_{j<K} e^{s/T} (for lse).
// ---------------------------------------------------------------------------
__global__ __launch_bounds__(256) void gemm_kernel(
    const u16* __restrict__ A1, const u16* __restrict__ A2,
    const u16* __restrict__ Wb,
    u16* __restrict__ S1, u16* __restrict__ S2,
    float* __restrict__ cs0_1, float* __restrict__ cs0_2,
    float* __restrict__ rowT1, float* __restrict__ rowT2)
{
    const int mat = blockIdx.z;
    const u16* A  = mat ? A2 : A1;
    u16* S        = mat ? S2 : S1;
    float* csum   = mat ? cs0_2 : cs0_1;
    float* rowT   = mat ? rowT2 : rowT1;
    const int bm = blockIdx.y, bn = blockIdx.x;

    __shared__ u16 At[128 * 64];
    __shared__ u16 Bt[128 * 64];
    __shared__ float sCol[128];
    __shared__ float sRow[128];

    const int tid  = threadIdx.x;
    const int wid  = tid >> 6, lane = tid & 63;
    const int wr   = wid >> 1, wc = wid & 1;

    f32x4 acc[4][4];
#pragma unroll
    for (int m = 0; m < 4; ++m)
#pragma unroll
        for (int n = 0; n < 4; ++n) {
            f32x4 z = {0.f, 0.f, 0.f, 0.f};
            acc[m][n] = z;
        }

    const int srow  = tid >> 3;                   // 0..31
    const int sslot = (tid & 7) ^ (srow & 7);     // swizzled source 16B slot
    const u16* Aga[4]; const u16* Bga[4]; u16* Ald[4]; u16* Bld[4];
#pragma unroll
    for (int r = 0; r < 4; ++r) {
        Aga[r] = A  + (size_t)(bm * 128 + r * 32 + srow) * D_ + sslot * 8;
        Bga[r] = Wb + (size_t)(bn * 128 + r * 32 + srow) * D_ + sslot * 8;
        Ald[r] = At + (r * 32 + srow) * 64 + (tid & 7) * 8;
        Bld[r] = Bt + (r * 32 + srow) * 64 + (tid & 7) * 8;
    }

    const int r15 = lane & 15, g = lane >> 4;
    const int sw0 = (g ^ (r15 & 7)) * 8;
    const int sw1 = ((g ^ (r15 & 7)) ^ 4) * 8;
    const u16* arow = At + (wr * 64 + r15) * 64;
    const u16* brow = Bt + (wc * 64 + r15) * 64;

    for (int kt = 0; kt < D_ / 64; ++kt) {
        const int ko = kt * 64;
#pragma unroll
        for (int r = 0; r < 4; ++r) {
            GLDS(Aga[r] + ko, Ald[r]);
            GLDS(Bga[r] + ko, Bld[r]);
        }
        __syncthreads();

        bf16x8 a[4], b[4];
#pragma unroll
        for (int m = 0; m < 4; ++m) a[m] = *reinterpret_cast<const bf16x8*>(arow + m * 16 * 64 + sw0);
#pragma unroll
        for (int n = 0; n < 4; ++n) b[n] = *reinterpret_cast<const bf16x8*>(brow + n * 16 * 64 + sw0);
#pragma unroll
        for (int m = 0; m < 4; ++m)
#pragma unroll
            for (int n = 0; n < 4; ++n)
                acc[m][n] = __builtin_amdgcn_mfma_f32_16x16x32_bf16(a[m], b[n], acc[m][n], 0, 0, 0);
#pragma unroll
        for (int m = 0; m < 4; ++m) a[m] = *reinterpret_cast<const bf16x8*>(arow + m * 16 * 64 + sw1);
#pragma unroll
        for (int n = 0; n < 4; ++n) b[n] = *reinterpret_cast<const bf16x8*>(brow + n * 16 * 64 + sw1);
#pragma unroll
        for (int m = 0; m < 4; ++m)
#pragma unroll
            for (int n = 0; n < 4; ++n)
                acc[m][n] = __builtin_amdgcn_mfma_f32_16x16x32_bf16(a[m], b[n], acc[m][n], 0, 0, 0);
        __syncthreads();
    }

    // ---- store scores as bf16 (C/D map: col=lane&15, row=(lane>>4)*4+r) ----
    const int lrow = wr * 64 + (lane >> 4) * 4;
    const int lcol = wc * 64 + (lane & 15);
#pragma unroll
    for (int m = 0; m < 4; ++m)
#pragma unroll
        for (int r = 0; r < 4; ++r) {
            u16* sp = S + (size_t)(bm * 128 + lrow + m * 16 + r) * KP + bn * 128 + lcol;
#pragma unroll
            for (int n = 0; n < 4; ++n) sp[n * 16] = f2bf(acc[m][n][r]);
        }

    // ---- fused reductions ----
    if (tid < 128) { sCol[tid] = 0.f; sRow[tid] = 0.f; }
    __syncthreads();

#pragma unroll
    for (int n = 0; n < 4; ++n) {
        float cs = 0.f;
#pragma unroll
        for (int m = 0; m < 4; ++m)
#pragma unroll
            for (int r = 0; r < 4; ++r) cs += __expf(acc[m][n][r] * INV_E);
        atomicAdd(&sCol[wc * 64 + n * 16 + (lane & 15)], cs);
    }

    const int gcol0 = bn * 128 + wc * 64 + (lane & 15);
#pragma unroll
    for (int m = 0; m < 4; ++m)
#pragma unroll
        for (int r = 0; r < 4; ++r) {
            float rs = 0.f;
#pragma unroll
            for (int n = 0; n < 4; ++n)
                if (gcol0 + n * 16 < K_) rs += __expf(acc[m][n][r] * INV_T);
            rs += __shfl_xor(rs, 1); rs += __shfl_xor(rs, 2);
            rs += __shfl_xor(rs, 4); rs += __shfl_xor(rs, 8);
            if ((lane & 15) == 0)
                atomicAdd(&sRow[wr * 64 + m * 16 + (lane >> 4) * 4 + r], rs);
        }
    __syncthreads();
    if (tid < 128) {
        atomicAdd(&csum[bn * 128 + tid], sCol[tid]);
        atomicAdd(&rowT[bm * 128 + tid], sRow[tid]);
    }
}

// ---------------------------------------------------------------------------
// FUSED row+col sinkhorn pass (one sweep of S does TWO sinkhorn half-steps):
//   per row i: u_i = 1/(B * sum_j E_ij * v_j),  v_j = 1/(K*cs_in_j)
//   then scatter cs_out_j += E_ij * u_i  into per-block LDS (padded layout,
//   2 copies, ds_add_f32 atomics), flushed once per block via global atomics.
// E kept in 48 fully-unrolled registers (no scratch). 8 rows/block.
// LDS pad: idx = j + (j>>5) -> per-lane bank = (8l + (l>>2)) % 32, 2-way max.
// ---------------------------------------------------------------------------
__global__ __launch_bounds__(256) void rowcol_kernel(
    const u16* __restrict__ S1, const u16* __restrict__ S2,
    const float* __restrict__ csinA, const float* __restrict__ csinB,
    float* __restrict__ csoutA, float* __restrict__ csoutB)
{
    const int mat = blockIdx.z;
    const u16* S      = mat ? S2 : S1;
    const float* csin = mat ? csinB : csinA;
    float* csout      = mat ? csoutB : csoutA;

    __shared__ float lds[2][3168];   // padded 3000 -> 3092, round up

    const int tid = threadIdx.x;
    const int wid = tid >> 6, lane = tid & 63;

    for (int t = tid; t < 2 * 3168; t += 256) ((float*)lds)[t] = 0.f;
    __syncthreads();

    const float4* cv = (const float4*)csin;
    float* myc = lds[wid >> 1];
    const int pb = lane * 8 + (lane >> 2);   // padded base for this lane

#pragma unroll
    for (int iter = 0; iter < 2; ++iter) {
        const int row = blockIdx.x * 8 + iter * 4 + wid;
        const uint4* sr = (const uint4*)(S + (size_t)row * KP);

        float ev[6][8];
        float acc = 0.f;
#pragma unroll
        for (int k = 0; k < 6; ++k) {
            const int c = lane + k * 64;
            if (k == 5 && c >= K_ / 8) {
#pragma unroll
                for (int e = 0; e < 8; ++e) ev[k][e] = 0.f;
            } else {
                uint4 v = sr[c];
                float4 ca = cv[2 * c], cb = cv[2 * c + 1];
                float f[8]; unpack8(v, f);
                const float w[8] = {ca.x, ca.y, ca.z, ca.w, cb.x, cb.y, cb.z, cb.w};
#pragma unroll
                for (int e = 0; e < 8; ++e) {
                    const float E = __expf(f[e] * INV_E);
                    ev[k][e] = E;
                    acc += E * __builtin_amdgcn_rcpf(3000.f * w[e]);
                }
            }
        }
#pragma unroll
        for (int m = 1; m < 64; m <<= 1) acc += __shfl_xor(acc, m);
        const float u = 1.f / (4096.f * acc);

#pragma unroll
        for (int k = 0; k < 6; ++k) {
            const bool ok = !(k == 5 && lane >= 55);   // c = lane+320 < 375
            if (ok) {
#pragma unroll
                for (int e = 0; e < 8; ++e)
                    atomicAdd(&myc[pb + 528 * k + e], ev[k][e] * u);
            }
        }
    }
    __syncthreads();

    for (int t = tid; t < K_; t += 256) {
        const int pt = t + (t >> 5);
        atomicAdd(&csout[t], lds[0][pt] + lds[1][pt]);
    }
}

// ---------------------------------------------------------------------------
// fused row3 + cross pass. Per row i (wave-per-row):
//   t1 = sum_j e^{s1/eps} v1_j,  d1 = sum_j e^{s1/eps} v1_j * s2_ij
//   t2 = sum_j e^{s2/eps} v2_j,  d2 = sum_j e^{s2/eps} v2_j * s1_ij
// cross[0] += d2/(B*t2); cross[1] += d1/(B*t1)
// ---------------------------------------------------------------------------
__global__ __launch_bounds__(256) void rowcross_kernel(
    const u16* __restrict__ S1, const u16* __restrict__ S2,
    const float* __restrict__ cs3_1, const float* __restrict__ cs3_2,
    float* __restrict__ cross)
{
    const int wid  = threadIdx.x >> 6, lane = threadIdx.x & 63;
    const int row  = blockIdx.x * 4 + wid;
    const uint4*  s1r = (const uint4*)(S1 + (size_t)row * KP);
    const uint4*  s2r = (const uint4*)(S2 + (size_t)row * KP);
    const float4* c1v = (const float4*)cs3_1;
    const float4* c2v = (const float4*)cs3_2;

    float t1 = 0.f, d1 = 0.f, t2 = 0.f, d2 = 0.f;
#pragma unroll
    for (int k = 0; k < 6; ++k) {
        const int c = lane + k * 64;
        if (k == 5 && c >= K_ / 8) break;
        uint4 va = s1r[c], vb = s2r[c];
        float4 p1a = c1v[2 * c], p1b = c1v[2 * c + 1];
        float4 p2a = c2v[2 * c], p2b = c2v[2 * c + 1];
        float f1[8], f2[8]; unpack8(va, f1); unpack8(vb, f2);
        const float w1[8] = {p1a.x, p1a.y, p1a.z, p1a.w, p1b.x, p1b.y, p1b.z, p1b.w};
        const float w2[8] = {p2a.x, p2a.y, p2a.z, p2a.w, p2b.x, p2b.y, p2b.z, p2b.w};
#pragma unroll
        for (int e = 0; e < 8; ++e) {
            const float e1 = __expf(f1[e] * INV_E) * __builtin_amdgcn_rcpf(3000.f * w1[e]);
            const float e2 = __expf(f2[e] * INV_E) * __builtin_amdgcn_rcpf(3000.f * w2[e]);
            t1 += e1; d1 += e1 * f2[e];
            t2 += e2; d2 += e2 * f1[e];
        }
    }
#pragma unroll
    for (int m = 1; m < 64; m <<= 1) {
        t1 += __shfl_xor(t1, m); d1 += __shfl_xor(d1, m);
        t2 += __shfl_xor(t2, m); d2 += __shfl_xor(d2, m);
    }
    __shared__ float sa[4], sb[4];
    if (lane == 0) {
        sa[wid] = d2 / (4096.f * t2);
        sb[wid] = d1 / (4096.f * t1);
    }
    __syncthreads();
    if (threadIdx.x == 0) {
        atomicAdd(&cross[0], sa[0] + sa[1] + sa[2] + sa[3]);
        atomicAdd(&cross[1], sb[0] + sb[1] + sb[2] + sb[3]);
    }
}

// ---------------------------------------------------------------------------
// finisher: loss = -0.5*[ (cross1+cross2)/(B*T) - (sum lse1 + sum lse2)/B^2 ]
// ---------------------------------------------------------------------------
__global__ __launch_bounds__(256) void finisher_kernel(
    const float* __restrict__ rowT1, const float* __restrict__ rowT2,
    const float* __restrict__ cross, float* __restrict__ out)
{
    float l = 0.f;
    for (int i = threadIdx.x; i < B_; i += 256)
        l += logf(rowT1[i]) + logf(rowT2[i]);
#pragma unroll
    for (int m = 1; m < 64; m <<= 1) l += __shfl_xor(l, m);
    __shared__ float s[4];
    if ((threadIdx.x & 63) == 0) s[threadIdx.x >> 6] = l;
    __syncthreads();
    if (threadIdx.x == 0) {
        const float sumlse = s[0] + s[1] + s[2] + s[3];
        const float t = (cross[0] + cross[1]) * (1.0f / (4096.0f * 0.1f));
        const float term = t - sumlse * (1.0f / (4096.0f * 4096.0f));
        out[0] = -0.5f * term;
    }
}

// ---------------------------------------------------------------------------
extern "C" void kernel_launch(void* const* d_in, const int* in_sizes, int n_in,
                              void* d_out, int out_size, void* d_ws, size_t ws_size,
                              hipStream_t stream)
{
    const float* z1 = (const float*)d_in[0];
    const float* z2 = (const float*)d_in[1];
    const float* W  = (const float*)d_in[2];
    float* out = (float*)d_out;

    char* p = (char*)d_ws;
    u16* A1 = (u16*)p; p += (size_t)B_ * D_ * 2;
    u16* A2 = (u16*)p; p += (size_t)B_ * D_ * 2;
    u16* Wb = (u16*)p; p += (size_t)KP * D_ * 2;
    u16* S1 = (u16*)p; p += (size_t)B_ * KP * 2;
    u16* S2 = (u16*)p; p += (size_t)B_ * KP * 2;
    float* cs0_1 = (float*)p; p += KP * 4;
    float* cs2_1 = (float*)p; p += KP * 4;
    float* cs3_1 = (float*)p; p += KP * 4;
    float* cs0_2 = (float*)p; p += KP * 4;
    float* cs2_2 = (float*)p; p += KP * 4;
    float* cs3_2 = (float*)p; p += KP * 4;
    float* rowT1 = (float*)p; p += B_ * 4;
    float* rowT2 = (float*)p; p += B_ * 4;
    float* cross = (float*)p; p += 16 * 4;

    // zero all atomic accumulators (cs0..cs3 x2, rowT x2, cross) in one memset
    const size_t zbytes = 6 * KP * 4 + 2 * B_ * 4 + 16 * 4;
    hipMemsetAsync(cs0_1, 0, zbytes, stream);

    convert_kernel<<<11264, 256, 0, stream>>>(z1, z2, W, A1, A2, Wb);

    gemm_kernel<<<dim3(KP / 128, B_ / 128, 2), 256, 0, stream>>>(
        A1, A2, Wb, S1, S2, cs0_1, cs0_2, rowT1, rowT2);

    // sinkhorn: cs0 fused in GEMM (u=1); then two fused row+col sweeps
    rowcol_kernel<<<dim3(B_ / 8, 1, 2), 256, 0, stream>>>(S1, S2, cs0_1, cs0_2, cs2_1, cs2_2);
    rowcol_kernel<<<dim3(B_ / 8, 1, 2), 256, 0, stream>>>(S1, S2, cs2_1, cs2_2, cs3_1, cs3_2);

    rowcross_kernel<<<dim3(B_ / 4, 1, 1), 256, 0, stream>>>(S1, S2, cs3_1, cs3_2, cross);
    finisher_kernel<<<1, 256, 0, stream>>>(rowT1, rowT2, cross, out);
}

// Round 5
// 433.058 us; speedup vs baseline: 1.0900x; 1.0900x over previous
//
#include <hip/hip_runtime.h>

typedef unsigned short u16;
typedef unsigned int   u32;
typedef __attribute__((ext_vector_type(4))) float  f32x4;
typedef __attribute__((ext_vector_type(8))) __bf16 bf16x8;

#define B_    4096
#define D_    1024
#define K_    3000
#define KP    3072
#define INV_T 10.0f
#define INV_E 20.0f

__device__ __forceinline__ u16 f2bf(float f) {  // round-to-nearest-even
    u32 u = __float_as_uint(f);
    u32 r = (u + 0x7fffu + ((u >> 16) & 1u)) >> 16;
    return (u16)r;
}
__device__ __forceinline__ void unpack8(uint4 v, float f[8]) {
    f[0] = __uint_as_float(v.x << 16); f[1] = __uint_as_float(v.x & 0xffff0000u);
    f[2] = __uint_as_float(v.y << 16); f[3] = __uint_as_float(v.y & 0xffff0000u);
    f[4] = __uint_as_float(v.z << 16); f[5] = __uint_as_float(v.z & 0xffff0000u);
    f[6] = __uint_as_float(v.w << 16); f[7] = __uint_as_float(v.w & 0xffff0000u);
}

#define GLDS(g, l) __builtin_amdgcn_global_load_lds( \
    (const __attribute__((address_space(1))) void*)(g), \
    (__attribute__((address_space(3))) void*)(l), 16, 0, 0)

// ---------------------------------------------------------------------------
// f32 -> bf16 conversion; W padded to KP rows with zeros.
// ---------------------------------------------------------------------------
__global__ __launch_bounds__(256) void convert_kernel(
    const float* __restrict__ z1, const float* __restrict__ z2,
    const float* __restrict__ W,
    u16* __restrict__ A1, u16* __restrict__ A2, u16* __restrict__ Wb)
{
    const int idx = blockIdx.x * 256 + threadIdx.x;
    const int n1 = B_ * D_ / 4;
    const int nW = KP * D_ / 4;
    ushort4 o;
    if (idx < n1) {
        float4 v = ((const float4*)z1)[idx];
        o.x = f2bf(v.x); o.y = f2bf(v.y); o.z = f2bf(v.z); o.w = f2bf(v.w);
        ((ushort4*)A1)[idx] = o;
    } else if (idx < 2 * n1) {
        const int j = idx - n1;
        float4 v = ((const float4*)z2)[j];
        o.x = f2bf(v.x); o.y = f2bf(v.y); o.z = f2bf(v.z); o.w = f2bf(v.w);
        ((ushort4*)A2)[j] = o;
    } else {
        const int j = idx - 2 * n1;
        if (j < nW) {
            const int row = j >> 8;
            if (row < K_) {
                float4 v = ((const float4*)W)[j];
                o.x = f2bf(v.x); o.y = f2bf(v.y); o.z = f2bf(v.z); o.w = f2bf(v.w);
            } else {
                o.x = 0; o.y = 0; o.z = 0; o.w = 0;
            }
            ((ushort4*)Wb)[j] = o;
        }
    }
}

// ---------------------------------------------------------------------------
// scores = z @ W^T. 128x128 tile, BK=64, 4 waves (2x2), 4x4 16x16x32 frags.
// LDS XOR-swizzle: 0 bank conflicts (verified round 3).
// Fused epilogue: bf16 score store, cs0 (col sums with u=1), rowT (lse).
// cs0 is written into half 0 of a [2][KP] buffer (half 1 stays zero).
// ---------------------------------------------------------------------------
__global__ __launch_bounds__(256) void gemm_kernel(
    const u16* __restrict__ A1, const u16* __restrict__ A2,
    const u16* __restrict__ Wb,
    u16* __restrict__ S1, u16* __restrict__ S2,
    float* __restrict__ cs0_1, float* __restrict__ cs0_2,
    float* __restrict__ rowT1, float* __restrict__ rowT2)
{
    const int mat = blockIdx.z;
    const u16* A  = mat ? A2 : A1;
    u16* S        = mat ? S2 : S1;
    float* csum   = mat ? cs0_2 : cs0_1;
    float* rowT   = mat ? rowT2 : rowT1;
    const int bm = blockIdx.y, bn = blockIdx.x;

    __shared__ u16 At[128 * 64];
    __shared__ u16 Bt[128 * 64];
    __shared__ float sCol[128];
    __shared__ float sRow[128];

    const int tid  = threadIdx.x;
    const int wid  = tid >> 6, lane = tid & 63;
    const int wr   = wid >> 1, wc = wid & 1;

    f32x4 acc[4][4];
#pragma unroll
    for (int m = 0; m < 4; ++m)
#pragma unroll
        for (int n = 0; n < 4; ++n) {
            f32x4 z = {0.f, 0.f, 0.f, 0.f};
            acc[m][n] = z;
        }

    const int srow  = tid >> 3;                   // 0..31
    const int sslot = (tid & 7) ^ (srow & 7);     // swizzled source 16B slot
    const u16* Aga[4]; const u16* Bga[4]; u16* Ald[4]; u16* Bld[4];
#pragma unroll
    for (int r = 0; r < 4; ++r) {
        Aga[r] = A  + (size_t)(bm * 128 + r * 32 + srow) * D_ + sslot * 8;
        Bga[r] = Wb + (size_t)(bn * 128 + r * 32 + srow) * D_ + sslot * 8;
        Ald[r] = At + (r * 32 + srow) * 64 + (tid & 7) * 8;
        Bld[r] = Bt + (r * 32 + srow) * 64 + (tid & 7) * 8;
    }

    const int r15 = lane & 15, g = lane >> 4;
    const int sw0 = (g ^ (r15 & 7)) * 8;
    const int sw1 = ((g ^ (r15 & 7)) ^ 4) * 8;
    const u16* arow = At + (wr * 64 + r15) * 64;
    const u16* brow = Bt + (wc * 64 + r15) * 64;

    for (int kt = 0; kt < D_ / 64; ++kt) {
        const int ko = kt * 64;
#pragma unroll
        for (int r = 0; r < 4; ++r) {
            GLDS(Aga[r] + ko, Ald[r]);
            GLDS(Bga[r] + ko, Bld[r]);
        }
        __syncthreads();

        bf16x8 a[4], b[4];
#pragma unroll
        for (int m = 0; m < 4; ++m) a[m] = *reinterpret_cast<const bf16x8*>(arow + m * 16 * 64 + sw0);
#pragma unroll
        for (int n = 0; n < 4; ++n) b[n] = *reinterpret_cast<const bf16x8*>(brow + n * 16 * 64 + sw0);
#pragma unroll
        for (int m = 0; m < 4; ++m)
#pragma unroll
            for (int n = 0; n < 4; ++n)
                acc[m][n] = __builtin_amdgcn_mfma_f32_16x16x32_bf16(a[m], b[n], acc[m][n], 0, 0, 0);
#pragma unroll
        for (int m = 0; m < 4; ++m) a[m] = *reinterpret_cast<const bf16x8*>(arow + m * 16 * 64 + sw1);
#pragma unroll
        for (int n = 0; n < 4; ++n) b[n] = *reinterpret_cast<const bf16x8*>(brow + n * 16 * 64 + sw1);
#pragma unroll
        for (int m = 0; m < 4; ++m)
#pragma unroll
            for (int n = 0; n < 4; ++n)
                acc[m][n] = __builtin_amdgcn_mfma_f32_16x16x32_bf16(a[m], b[n], acc[m][n], 0, 0, 0);
        __syncthreads();
    }

    // ---- store scores as bf16 (C/D map: col=lane&15, row=(lane>>4)*4+r) ----
    const int lrow = wr * 64 + (lane >> 4) * 4;
    const int lcol = wc * 64 + (lane & 15);
#pragma unroll
    for (int m = 0; m < 4; ++m)
#pragma unroll
        for (int r = 0; r < 4; ++r) {
            u16* sp = S + (size_t)(bm * 128 + lrow + m * 16 + r) * KP + bn * 128 + lcol;
#pragma unroll
            for (int n = 0; n < 4; ++n) sp[n * 16] = f2bf(acc[m][n][r]);
        }

    // ---- fused reductions ----
    if (tid < 128) { sCol[tid] = 0.f; sRow[tid] = 0.f; }
    __syncthreads();

#pragma unroll
    for (int n = 0; n < 4; ++n) {
        float cs = 0.f;
#pragma unroll
        for (int m = 0; m < 4; ++m)
#pragma unroll
            for (int r = 0; r < 4; ++r) cs += __expf(acc[m][n][r] * INV_E);
        atomicAdd(&sCol[wc * 64 + n * 16 + (lane & 15)], cs);
    }

    const int gcol0 = bn * 128 + wc * 64 + (lane & 15);
#pragma unroll
    for (int m = 0; m < 4; ++m)
#pragma unroll
        for (int r = 0; r < 4; ++r) {
            float rs = 0.f;
#pragma unroll
            for (int n = 0; n < 4; ++n)
                if (gcol0 + n * 16 < K_) rs += __expf(acc[m][n][r] * INV_T);
            rs += __shfl_xor(rs, 1); rs += __shfl_xor(rs, 2);
            rs += __shfl_xor(rs, 4); rs += __shfl_xor(rs, 8);
            if ((lane & 15) == 0)
                atomicAdd(&sRow[wr * 64 + m * 16 + (lane >> 4) * 4 + r], rs);
        }
    __syncthreads();
    if (tid < 128) {
        atomicAdd(&csum[bn * 128 + tid], sCol[tid]);
        atomicAdd(&rowT[bm * 128 + tid], sRow[tid]);
    }
}

// ---------------------------------------------------------------------------
// FUSED row+col sinkhorn pass, two-phase (no E cache, no LDS atomics):
//  Phase A: wave-per-row row sums -> u_i for 16 rows (su[] in LDS).
//  Phase B: re-read the same 16 rows (L2-hot) in column slabs; each thread
//           accumulates 8 (or 16) columns in REGISTERS, then one global
//           atomicAdd per column into csout[2][KP] (block-parity buffer
//           halves the same-address contention).
// csin is [2][KP]; v_j = 1/(K * (csin[0][j]+csin[1][j])).
// ---------------------------------------------------------------------------
__global__ __launch_bounds__(256) void rowcol_kernel(
    const u16* __restrict__ S1, const u16* __restrict__ S2,
    const float* __restrict__ csinA, const float* __restrict__ csinB,
    float* __restrict__ csoutA, float* __restrict__ csoutB)
{
    const int mat = blockIdx.z;
    const u16* S      = mat ? S2 : S1;
    const float* csin = mat ? csinB : csinA;
    float* csout      = (mat ? csoutB : csoutA) + (blockIdx.x & 1) * KP;

    __shared__ float su[16];

    const int tid = threadIdx.x, wid = tid >> 6, lane = tid & 63;
    const float4* cv0 = (const float4*)csin;
    const float4* cv1 = (const float4*)(csin + KP);

    // ---- Phase A: row sums -> u for rows [bx*16, bx*16+16) ----
#pragma unroll
    for (int it = 0; it < 4; ++it) {
        const int row = blockIdx.x * 16 + it * 4 + wid;
        const uint4* sr = (const uint4*)(S + (size_t)row * KP);
        float acc = 0.f;
#pragma unroll
        for (int k = 0; k < 6; ++k) {
            const int c = lane + k * 64;
            if (k == 5 && c >= K_ / 8) continue;
            uint4 v = sr[c];
            float4 a0 = cv0[2 * c], a1 = cv0[2 * c + 1];
            float4 b0 = cv1[2 * c], b1 = cv1[2 * c + 1];
            float f[8]; unpack8(v, f);
            const float w[8] = {a0.x + b0.x, a0.y + b0.y, a0.z + b0.z, a0.w + b0.w,
                                a1.x + b1.x, a1.y + b1.y, a1.z + b1.z, a1.w + b1.w};
#pragma unroll
            for (int e = 0; e < 8; ++e)
                acc += __expf(f[e] * INV_E) * __builtin_amdgcn_rcpf(3000.f * w[e]);
        }
#pragma unroll
        for (int m = 1; m < 64; m <<= 1) acc += __shfl_xor(acc, m);
        if (lane == 0) su[it * 4 + wid] = 1.f / (4096.f * acc);
    }
    __syncthreads();

    // ---- Phase B: column partials in registers over the 16 rows ----
    const int c0 = tid * 8;           // columns 0..2047
    const int c1 = 2048 + tid * 8;    // columns 2048..2999 (tid < 119)
    float p0[8] = {0.f, 0.f, 0.f, 0.f, 0.f, 0.f, 0.f, 0.f};
    float p1[8] = {0.f, 0.f, 0.f, 0.f, 0.f, 0.f, 0.f, 0.f};
    const u16* Sb = S + (size_t)(blockIdx.x * 16) * KP;
#pragma unroll 4
    for (int r = 0; r < 16; ++r) {
        const float ui = su[r];
        uint4 v = *(const uint4*)(Sb + (size_t)r * KP + c0);
        float f[8]; unpack8(v, f);
#pragma unroll
        for (int e = 0; e < 8; ++e) p0[e] += __expf(f[e] * INV_E) * ui;
        if (tid < 119) {
            uint4 v2 = *(const uint4*)(Sb + (size_t)r * KP + c1);
            float gg[8]; unpack8(v2, gg);
#pragma unroll
            for (int e = 0; e < 8; ++e) p1[e] += __expf(gg[e] * INV_E) * ui;
        }
    }
#pragma unroll
    for (int e = 0; e < 8; ++e) atomicAdd(&csout[c0 + e], p0[e]);
    if (tid < 119) {
#pragma unroll
        for (int e = 0; e < 8; ++e) atomicAdd(&csout[c1 + e], p1[e]);
    }
}

// ---------------------------------------------------------------------------
// fused row3 + cross pass. Per row i (wave-per-row):
//   t1 = sum_j e^{s1/eps} v1_j,  d1 = sum_j e^{s1/eps} v1_j * s2_ij
//   t2 = sum_j e^{s2/eps} v2_j,  d2 = sum_j e^{s2/eps} v2_j * s1_ij
// cross[0] += d2/(B*t2); cross[1] += d1/(B*t1).  cs3 is [2][KP].
// ---------------------------------------------------------------------------
__global__ __launch_bounds__(256) void rowcross_kernel(
    const u16* __restrict__ S1, const u16* __restrict__ S2,
    const float* __restrict__ cs3_1, const float* __restrict__ cs3_2,
    float* __restrict__ cross)
{
    const int wid  = threadIdx.x >> 6, lane = threadIdx.x & 63;
    const int row  = blockIdx.x * 4 + wid;
    const uint4*  s1r = (const uint4*)(S1 + (size_t)row * KP);
    const uint4*  s2r = (const uint4*)(S2 + (size_t)row * KP);
    const float4* c1a = (const float4*)cs3_1;
    const float4* c1b = (const float4*)(cs3_1 + KP);
    const float4* c2a = (const float4*)cs3_2;
    const float4* c2b = (const float4*)(cs3_2 + KP);

    float t1 = 0.f, d1 = 0.f, t2 = 0.f, d2 = 0.f;
#pragma unroll
    for (int k = 0; k < 6; ++k) {
        const int c = lane + k * 64;
        if (k == 5 && c >= K_ / 8) break;
        uint4 va = s1r[c], vb = s2r[c];
        float4 xa0 = c1a[2 * c], xa1 = c1a[2 * c + 1];
        float4 xb0 = c1b[2 * c], xb1 = c1b[2 * c + 1];
        float4 ya0 = c2a[2 * c], ya1 = c2a[2 * c + 1];
        float4 yb0 = c2b[2 * c], yb1 = c2b[2 * c + 1];
        float f1[8], f2[8]; unpack8(va, f1); unpack8(vb, f2);
        const float w1[8] = {xa0.x + xb0.x, xa0.y + xb0.y, xa0.z + xb0.z, xa0.w + xb0.w,
                             xa1.x + xb1.x, xa1.y + xb1.y, xa1.z + xb1.z, xa1.w + xb1.w};
        const float w2[8] = {ya0.x + yb0.x, ya0.y + yb0.y, ya0.z + yb0.z, ya0.w + yb0.w,
                             ya1.x + yb1.x, ya1.y + yb1.y, ya1.z + yb1.z, ya1.w + yb1.w};
#pragma unroll
        for (int e = 0; e < 8; ++e) {
            const float e1 = __expf(f1[e] * INV_E) * __builtin_amdgcn_rcpf(3000.f * w1[e]);
            const float e2 = __expf(f2[e] * INV_E) * __builtin_amdgcn_rcpf(3000.f * w2[e]);
            t1 += e1; d1 += e1 * f2[e];
            t2 += e2; d2 += e2 * f1[e];
        }
    }
#pragma unroll
    for (int m = 1; m < 64; m <<= 1) {
        t1 += __shfl_xor(t1, m); d1 += __shfl_xor(d1, m);
        t2 += __shfl_xor(t2, m); d2 += __shfl_xor(d2, m);
    }
    __shared__ float sa[4], sb[4];
    if (lane == 0) {
        sa[wid] = d2 / (4096.f * t2);
        sb[wid] = d1 / (4096.f * t1);
    }
    __syncthreads();
    if (threadIdx.x == 0) {
        atomicAdd(&cross[0], sa[0] + sa[1] + sa[2] + sa[3]);
        atomicAdd(&cross[1], sb[0] + sb[1] + sb[2] + sb[3]);
    }
}

// ---------------------------------------------------------------------------
// finisher: loss = -0.5*[ (cross1+cross2)/(B*T) - (sum lse1 + sum lse2)/B^2 ]
// ---------------------------------------------------------------------------
__global__ __launch_bounds__(256) void finisher_kernel(
    const float* __restrict__ rowT1, const float* __restrict__ rowT2,
    const float* __restrict__ cross, float* __restrict__ out)
{
    float l = 0.f;
    for (int i = threadIdx.x; i < B_; i += 256)
        l += logf(rowT1[i]) + logf(rowT2[i]);
#pragma unroll
    for (int m = 1; m < 64; m <<= 1) l += __shfl_xor(l, m);
    __shared__ float s[4];
    if ((threadIdx.x & 63) == 0) s[threadIdx.x >> 6] = l;
    __syncthreads();
    if (threadIdx.x == 0) {
        const float sumlse = s[0] + s[1] + s[2] + s[3];
        const float t = (cross[0] + cross[1]) * (1.0f / (4096.0f * 0.1f));
        const float term = t - sumlse * (1.0f / (4096.0f * 4096.0f));
        out[0] = -0.5f * term;
    }
}

// ---------------------------------------------------------------------------
extern "C" void kernel_launch(void* const* d_in, const int* in_sizes, int n_in,
                              void* d_out, int out_size, void* d_ws, size_t ws_size,
                              hipStream_t stream)
{
    const float* z1 = (const float*)d_in[0];
    const float* z2 = (const float*)d_in[1];
    const float* W  = (const float*)d_in[2];
    float* out = (float*)d_out;

    char* p = (char*)d_ws;
    u16* A1 = (u16*)p; p += (size_t)B_ * D_ * 2;
    u16* A2 = (u16*)p; p += (size_t)B_ * D_ * 2;
    u16* Wb = (u16*)p; p += (size_t)KP * D_ * 2;
    u16* S1 = (u16*)p; p += (size_t)B_ * KP * 2;
    u16* S2 = (u16*)p; p += (size_t)B_ * KP * 2;
    // cs buffers are [2][KP] (two partial halves; consumers sum them)
    float* cs0_1 = (float*)p; p += 2 * KP * 4;
    float* cs2_1 = (float*)p; p += 2 * KP * 4;
    float* cs3_1 = (float*)p; p += 2 * KP * 4;
    float* cs0_2 = (float*)p; p += 2 * KP * 4;
    float* cs2_2 = (float*)p; p += 2 * KP * 4;
    float* cs3_2 = (float*)p; p += 2 * KP * 4;
    float* rowT1 = (float*)p; p += B_ * 4;
    float* rowT2 = (float*)p; p += B_ * 4;
    float* cross = (float*)p; p += 16 * 4;

    // zero all atomic accumulators (cs x6 double-buffers, rowT x2, cross)
    const size_t zbytes = 12 * KP * 4 + 2 * B_ * 4 + 16 * 4;
    hipMemsetAsync(cs0_1, 0, zbytes, stream);

    convert_kernel<<<11264, 256, 0, stream>>>(z1, z2, W, A1, A2, Wb);

    gemm_kernel<<<dim3(KP / 128, B_ / 128, 2), 256, 0, stream>>>(
        A1, A2, Wb, S1, S2, cs0_1, cs0_2, rowT1, rowT2);

    // sinkhorn: cs0 fused in GEMM (u=1); then two fused row+col sweeps
    rowcol_kernel<<<dim3(B_ / 16, 1, 2), 256, 0, stream>>>(S1, S2, cs0_1, cs0_2, cs2_1, cs2_2);
    rowcol_kernel<<<dim3(B_ / 16, 1, 2), 256, 0, stream>>>(S1, S2, cs2_1, cs2_2, cs3_1, cs3_2);

    rowcross_kernel<<<dim3(B_ / 4, 1, 1), 256, 0, stream>>>(S1, S2, cs3_1, cs3_2, cross);
    finisher_kernel<<<1, 256, 0, stream>>>(rowT1, rowT2, cross, out);
}

// Round 8
// 329.707 us; speedup vs baseline: 1.4317x; 1.3135x over previous
//
#include <hip/hip_runtime.h>

typedef unsigned short u16;
typedef unsigned int   u32;
typedef __attribute__((ext_vector_type(4))) float  f32x4;
typedef __attribute__((ext_vector_type(8))) __bf16 bf16x8;

#define B_    4096
#define D_    1024
#define K_    3000
#define KP    3072
#define INV_T 10.0f
#define INV_E 20.0f
#define NPART 512   // rowcol partial slices per matrix (one per block)

__device__ __forceinline__ u16 f2bf(float f) {  // round-to-nearest-even
    u32 u = __float_as_uint(f);
    u32 r = (u + 0x7fffu + ((u >> 16) & 1u)) >> 16;
    return (u16)r;
}
__device__ __forceinline__ void unpack8(uint4 v, float f[8]) {
    f[0] = __uint_as_float(v.x << 16); f[1] = __uint_as_float(v.x & 0xffff0000u);
    f[2] = __uint_as_float(v.y << 16); f[3] = __uint_as_float(v.y & 0xffff0000u);
    f[4] = __uint_as_float(v.z << 16); f[5] = __uint_as_float(v.z & 0xffff0000u);
    f[6] = __uint_as_float(v.w << 16); f[7] = __uint_as_float(v.w & 0xffff0000u);
}

#define GLDS(g, l) __builtin_amdgcn_global_load_lds( \
    (const __attribute__((address_space(1))) void*)(g), \
    (__attribute__((address_space(3))) void*)(l), 16, 0, 0)

// ---------------------------------------------------------------------------
// f32 -> bf16 conversion; W padded to KP rows with zeros.
// ---------------------------------------------------------------------------
__global__ __launch_bounds__(256) void convert_kernel(
    const float* __restrict__ z1, const float* __restrict__ z2,
    const float* __restrict__ W,
    u16* __restrict__ A1, u16* __restrict__ A2, u16* __restrict__ Wb)
{
    const int idx = blockIdx.x * 256 + threadIdx.x;
    const int n1 = B_ * D_ / 4;
    const int nW = KP * D_ / 4;
    ushort4 o;
    if (idx < n1) {
        float4 v = ((const float4*)z1)[idx];
        o.x = f2bf(v.x); o.y = f2bf(v.y); o.z = f2bf(v.z); o.w = f2bf(v.w);
        ((ushort4*)A1)[idx] = o;
    } else if (idx < 2 * n1) {
        const int j = idx - n1;
        float4 v = ((const float4*)z2)[j];
        o.x = f2bf(v.x); o.y = f2bf(v.y); o.z = f2bf(v.z); o.w = f2bf(v.w);
        ((ushort4*)A2)[j] = o;
    } else {
        const int j = idx - 2 * n1;
        if (j < nW) {
            const int row = j >> 8;
            if (row < K_) {
                float4 v = ((const float4*)W)[j];
                o.x = f2bf(v.x); o.y = f2bf(v.y); o.z = f2bf(v.z); o.w = f2bf(v.w);
            } else {
                o.x = 0; o.y = 0; o.z = 0; o.w = 0;
            }
            ((ushort4*)Wb)[j] = o;
        }
    }
}

// ---------------------------------------------------------------------------
// scores = z @ W^T. 128x128 tile, BK=64, 4 waves (2x2), 4x4 16x16x32 frags.
// LDS XOR-swizzle: 0 bank conflicts (verified round 3).
// Fused epilogue: bf16 score store, cs0 partial (col sums, u=1) as PLAIN
// stores into cs0part[bm][KP] slice, rowT (lse) via global atomics.
// ---------------------------------------------------------------------------
__global__ __launch_bounds__(256) void gemm_kernel(
    const u16* __restrict__ A1, const u16* __restrict__ A2,
    const u16* __restrict__ Wb,
    u16* __restrict__ S1, u16* __restrict__ S2,
    float* __restrict__ cs0pA, float* __restrict__ cs0pB,
    float* __restrict__ rowT1, float* __restrict__ rowT2)
{
    const int mat = blockIdx.z;
    const u16* A  = mat ? A2 : A1;
    u16* S        = mat ? S2 : S1;
    float* rowT   = mat ? rowT2 : rowT1;
    const int bm = blockIdx.y, bn = blockIdx.x;
    float* cs0p   = (mat ? cs0pB : cs0pA) + (size_t)bm * KP;

    __shared__ u16 At[128 * 64];
    __shared__ u16 Bt[128 * 64];
    __shared__ float sCol[128];
    __shared__ float sRow[128];

    const int tid  = threadIdx.x;
    const int wid  = tid >> 6, lane = tid & 63;
    const int wr   = wid >> 1, wc = wid & 1;

    f32x4 acc[4][4];
#pragma unroll
    for (int m = 0; m < 4; ++m)
#pragma unroll
        for (int n = 0; n < 4; ++n) {
            f32x4 z = {0.f, 0.f, 0.f, 0.f};
            acc[m][n] = z;
        }

    const int srow  = tid >> 3;                   // 0..31
    const int sslot = (tid & 7) ^ (srow & 7);     // swizzled source 16B slot
    const u16* Aga[4]; const u16* Bga[4]; u16* Ald[4]; u16* Bld[4];
#pragma unroll
    for (int r = 0; r < 4; ++r) {
        Aga[r] = A  + (size_t)(bm * 128 + r * 32 + srow) * D_ + sslot * 8;
        Bga[r] = Wb + (size_t)(bn * 128 + r * 32 + srow) * D_ + sslot * 8;
        Ald[r] = At + (r * 32 + srow) * 64 + (tid & 7) * 8;
        Bld[r] = Bt + (r * 32 + srow) * 64 + (tid & 7) * 8;
    }

    const int r15 = lane & 15, g = lane >> 4;
    const int sw0 = (g ^ (r15 & 7)) * 8;
    const int sw1 = ((g ^ (r15 & 7)) ^ 4) * 8;
    const u16* arow = At + (wr * 64 + r15) * 64;
    const u16* brow = Bt + (wc * 64 + r15) * 64;

    for (int kt = 0; kt < D_ / 64; ++kt) {
        const int ko = kt * 64;
#pragma unroll
        for (int r = 0; r < 4; ++r) {
            GLDS(Aga[r] + ko, Ald[r]);
            GLDS(Bga[r] + ko, Bld[r]);
        }
        __syncthreads();

        bf16x8 a[4], b[4];
#pragma unroll
        for (int m = 0; m < 4; ++m) a[m] = *reinterpret_cast<const bf16x8*>(arow + m * 16 * 64 + sw0);
#pragma unroll
        for (int n = 0; n < 4; ++n) b[n] = *reinterpret_cast<const bf16x8*>(brow + n * 16 * 64 + sw0);
#pragma unroll
        for (int m = 0; m < 4; ++m)
#pragma unroll
            for (int n = 0; n < 4; ++n)
                acc[m][n] = __builtin_amdgcn_mfma_f32_16x16x32_bf16(a[m], b[n], acc[m][n], 0, 0, 0);
#pragma unroll
        for (int m = 0; m < 4; ++m) a[m] = *reinterpret_cast<const bf16x8*>(arow + m * 16 * 64 + sw1);
#pragma unroll
        for (int n = 0; n < 4; ++n) b[n] = *reinterpret_cast<const bf16x8*>(brow + n * 16 * 64 + sw1);
#pragma unroll
        for (int m = 0; m < 4; ++m)
#pragma unroll
            for (int n = 0; n < 4; ++n)
                acc[m][n] = __builtin_amdgcn_mfma_f32_16x16x32_bf16(a[m], b[n], acc[m][n], 0, 0, 0);
        __syncthreads();
    }

    // ---- store scores as bf16 (C/D map: col=lane&15, row=(lane>>4)*4+r) ----
    const int lrow = wr * 64 + (lane >> 4) * 4;
    const int lcol = wc * 64 + (lane & 15);
#pragma unroll
    for (int m = 0; m < 4; ++m)
#pragma unroll
        for (int r = 0; r < 4; ++r) {
            u16* sp = S + (size_t)(bm * 128 + lrow + m * 16 + r) * KP + bn * 128 + lcol;
#pragma unroll
            for (int n = 0; n < 4; ++n) sp[n * 16] = f2bf(acc[m][n][r]);
        }

    // ---- fused reductions ----
    if (tid < 128) { sCol[tid] = 0.f; sRow[tid] = 0.f; }
    __syncthreads();

#pragma unroll
    for (int n = 0; n < 4; ++n) {
        float cs = 0.f;
#pragma unroll
        for (int m = 0; m < 4; ++m)
#pragma unroll
            for (int r = 0; r < 4; ++r) cs += __expf(acc[m][n][r] * INV_E);
        atomicAdd(&sCol[wc * 64 + n * 16 + (lane & 15)], cs);
    }

    const int gcol0 = bn * 128 + wc * 64 + (lane & 15);
#pragma unroll
    for (int m = 0; m < 4; ++m)
#pragma unroll
        for (int r = 0; r < 4; ++r) {
            float rs = 0.f;
#pragma unroll
            for (int n = 0; n < 4; ++n)
                if (gcol0 + n * 16 < K_) rs += __expf(acc[m][n][r] * INV_T);
            rs += __shfl_xor(rs, 1); rs += __shfl_xor(rs, 2);
            rs += __shfl_xor(rs, 4); rs += __shfl_xor(rs, 8);
            if ((lane & 15) == 0)
                atomicAdd(&sRow[wr * 64 + m * 16 + (lane >> 4) * 4 + r], rs);
        }
    __syncthreads();
    if (tid < 128) {
        cs0p[bn * 128 + tid] = sCol[tid];                 // plain partial store
        atomicAdd(&rowT[bm * 128 + tid], sRow[tid]);
    }
}

// ---------------------------------------------------------------------------
// reducev: v[j] = 1/(K * sum_p part[p][j]).  Folds the Sinkhorn col-normalizer
// reciprocal so downstream sweeps just multiply. P = 32 (gemm) or 512 (rowcol).
// ---------------------------------------------------------------------------
__global__ __launch_bounds__(256) void reducev_kernel(
    const float* __restrict__ partA, const float* __restrict__ partB, int P,
    float* __restrict__ voutA, float* __restrict__ voutB)
{
    const int mat = blockIdx.z;
    const float* part = mat ? partB : partA;
    float* vout       = mat ? voutB : voutA;
    const int j = blockIdx.x * 256 + threadIdx.x;
    float a0 = 0.f, a1 = 0.f, a2 = 0.f, a3 = 0.f;
    int p = 0;
    for (; p + 4 <= P; p += 4) {
        a0 += part[(size_t)p * KP + j];
        a1 += part[(size_t)(p + 1) * KP + j];
        a2 += part[(size_t)(p + 2) * KP + j];
        a3 += part[(size_t)(p + 3) * KP + j];
    }
    for (; p < P; ++p) a0 += part[(size_t)p * KP + j];
    vout[j] = __builtin_amdgcn_rcpf(3000.f * ((a0 + a1) + (a2 + a3)));
}

// ---------------------------------------------------------------------------
// FUSED row+col sinkhorn sweep, full occupancy, zero atomics:
//  Phase A: wave w (of 8) computes u for row bx*8+w: u = 1/(B*sum_j E_ij v_j)
//  Phase B: threads 0..374 each own 8 cols; accumulate E_ij*u_i over the 8
//           L2-hot rows in registers; plain float4 store to part[bx][cols].
// ---------------------------------------------------------------------------
__global__ __launch_bounds__(512) void rowcol_kernel(
    const u16* __restrict__ S1, const u16* __restrict__ S2,
    const float* __restrict__ vinA, const float* __restrict__ vinB,
    float* __restrict__ partA, float* __restrict__ partB)
{
    const int mat = blockIdx.z;
    const u16* S     = mat ? S2 : S1;
    const float* vin = mat ? vinB : vinA;
    float* part      = (mat ? partB : partA) + (size_t)blockIdx.x * KP;

    __shared__ float su[8];
    const int tid = threadIdx.x, wid = tid >> 6, lane = tid & 63;

    // ---- Phase A ----
    const int row = blockIdx.x * 8 + wid;
    const uint4*  sr = (const uint4*)(S + (size_t)row * KP);
    const float4* vv = (const float4*)vin;
    float acc = 0.f;
#pragma unroll
    for (int k = 0; k < 6; ++k) {
        const int c = lane + k * 64;
        if (k == 5 && c >= K_ / 8) continue;
        uint4 v = sr[c];
        float4 w0 = vv[2 * c], w1 = vv[2 * c + 1];
        float f[8]; unpack8(v, f);
        acc += __expf(f[0] * INV_E) * w0.x;
        acc += __expf(f[1] * INV_E) * w0.y;
        acc += __expf(f[2] * INV_E) * w0.z;
        acc += __expf(f[3] * INV_E) * w0.w;
        acc += __expf(f[4] * INV_E) * w1.x;
        acc += __expf(f[5] * INV_E) * w1.y;
        acc += __expf(f[6] * INV_E) * w1.z;
        acc += __expf(f[7] * INV_E) * w1.w;
    }
#pragma unroll
    for (int m = 1; m < 64; m <<= 1) acc += __shfl_xor(acc, m);
    if (lane == 0) su[wid] = 1.f / (4096.f * acc);
    __syncthreads();

    // ---- Phase B ----
    if (tid < K_ / 8) {
        const int c0 = tid * 8;
        float p[8] = {0.f, 0.f, 0.f, 0.f, 0.f, 0.f, 0.f, 0.f};
        const u16* Sb = S + (size_t)(blockIdx.x * 8) * KP;
#pragma unroll
        for (int r = 0; r < 8; ++r) {
            const float ui = su[r];
            uint4 v = *(const uint4*)(Sb + (size_t)r * KP + c0);
            float f[8]; unpack8(v, f);
#pragma unroll
            for (int e = 0; e < 8; ++e) p[e] += __expf(f[e] * INV_E) * ui;
        }
        float4* op = (float4*)(part + c0);
        op[0] = make_float4(p[0], p[1], p[2], p[3]);
        op[1] = make_float4(p[4], p[5], p[6], p[7]);
    }
}

// ---------------------------------------------------------------------------
// fused row3 + cross pass. Per row i (wave-per-row), with precomputed v:
//   t1 = sum_j E1*v1,  d1 = sum_j E1*v1*s2;  t2, d2 symmetric.
// cross[0] += d2/(B*t2); cross[1] += d1/(B*t1)
// ---------------------------------------------------------------------------
__global__ __launch_bounds__(256) void rowcross_kernel(
    const u16* __restrict__ S1, const u16* __restrict__ S2,
    const float* __restrict__ v3_1, const float* __restrict__ v3_2,
    float* __restrict__ cross)
{
    const int wid  = threadIdx.x >> 6, lane = threadIdx.x & 63;
    const int row  = blockIdx.x * 4 + wid;
    const uint4*  s1r = (const uint4*)(S1 + (size_t)row * KP);
    const uint4*  s2r = (const uint4*)(S2 + (size_t)row * KP);
    const float4* v1v = (const float4*)v3_1;
    const float4* v2v = (const float4*)v3_2;

    float t1 = 0.f, d1 = 0.f, t2 = 0.f, d2 = 0.f;
#pragma unroll
    for (int k = 0; k < 6; ++k) {
        const int c = lane + k * 64;
        if (k == 5 && c >= K_ / 8) break;
        uint4 va = s1r[c], vb = s2r[c];
        float4 x0 = v1v[2 * c], x1 = v1v[2 * c + 1];
        float4 y0 = v2v[2 * c], y1 = v2v[2 * c + 1];
        float f1[8], f2[8]; unpack8(va, f1); unpack8(vb, f2);
        const float w1[8] = {x0.x, x0.y, x0.z, x0.w, x1.x, x1.y, x1.z, x1.w};
        const float w2[8] = {y0.x, y0.y, y0.z, y0.w, y1.x, y1.y, y1.z, y1.w};
#pragma unroll
        for (int e = 0; e < 8; ++e) {
            const float e1 = __expf(f1[e] * INV_E) * w1[e];
            const float e2 = __expf(f2[e] * INV_E) * w2[e];
            t1 += e1; d1 += e1 * f2[e];
            t2 += e2; d2 += e2 * f1[e];
        }
    }
#pragma unroll
    for (int m = 1; m < 64; m <<= 1) {
        t1 += __shfl_xor(t1, m); d1 += __shfl_xor(d1, m);
        t2 += __shfl_xor(t2, m); d2 += __shfl_xor(d2, m);
    }
    __shared__ float sa[4], sb[4];
    if (lane == 0) {
        sa[wid] = d2 / (4096.f * t2);
        sb[wid] = d1 / (4096.f * t1);
    }
    __syncthreads();
    if (threadIdx.x == 0) {
        atomicAdd(&cross[0], sa[0] + sa[1] + sa[2] + sa[3]);
        atomicAdd(&cross[1], sb[0] + sb[1] + sb[2] + sb[3]);
    }
}

// ---------------------------------------------------------------------------
// finisher: loss = -0.5*[ (cross1+cross2)/(B*T) - (sum lse1 + sum lse2)/B^2 ]
// ---------------------------------------------------------------------------
__global__ __launch_bounds__(256) void finisher_kernel(
    const float* __restrict__ rowT1, const float* __restrict__ rowT2,
    const float* __restrict__ cross, float* __restrict__ out)
{
    float l = 0.f;
    for (int i = threadIdx.x; i < B_; i += 256)
        l += logf(rowT1[i]) + logf(rowT2[i]);
#pragma unroll
    for (int m = 1; m < 64; m <<= 1) l += __shfl_xor(l, m);
    __shared__ float s[4];
    if ((threadIdx.x & 63) == 0) s[threadIdx.x >> 6] = l;
    __syncthreads();
    if (threadIdx.x == 0) {
        const float sumlse = s[0] + s[1] + s[2] + s[3];
        const float t = (cross[0] + cross[1]) * (1.0f / (4096.0f * 0.1f));
        const float term = t - sumlse * (1.0f / (4096.0f * 4096.0f));
        out[0] = -0.5f * term;
    }
}

// ---------------------------------------------------------------------------
extern "C" void kernel_launch(void* const* d_in, const int* in_sizes, int n_in,
                              void* d_out, int out_size, void* d_ws, size_t ws_size,
                              hipStream_t stream)
{
    const float* z1 = (const float*)d_in[0];
    const float* z2 = (const float*)d_in[1];
    const float* W  = (const float*)d_in[2];
    float* out = (float*)d_out;

    char* p = (char*)d_ws;
    u16* A1 = (u16*)p; p += (size_t)B_ * D_ * 2;
    u16* A2 = (u16*)p; p += (size_t)B_ * D_ * 2;
    u16* Wb = (u16*)p; p += (size_t)KP * D_ * 2;
    u16* S1 = (u16*)p; p += (size_t)B_ * KP * 2;
    u16* S2 = (u16*)p; p += (size_t)B_ * KP * 2;
    float* cs0pA = (float*)p; p += (size_t)32 * KP * 4;       // gemm partials
    float* cs0pB = (float*)p; p += (size_t)32 * KP * 4;
    float* partA = (float*)p; p += (size_t)NPART * KP * 4;    // rowcol partials
    float* partB = (float*)p; p += (size_t)NPART * KP * 4;
    float* v0A = (float*)p; p += KP * 4;
    float* v0B = (float*)p; p += KP * 4;
    float* v2A = (float*)p; p += KP * 4;
    float* v2B = (float*)p; p += KP * 4;
    float* v3A = (float*)p; p += KP * 4;
    float* v3B = (float*)p; p += KP * 4;
    float* rowT1 = (float*)p; p += B_ * 4;   // atomic accumulators (zeroed)
    float* rowT2 = (float*)p; p += B_ * 4;
    float* cross = (float*)p; p += 16 * 4;

    // zero only the atomic accumulators: rowT1, rowT2, cross (contiguous)
    hipMemsetAsync(rowT1, 0, 2 * B_ * 4 + 16 * 4, stream);

    convert_kernel<<<11264, 256, 0, stream>>>(z1, z2, W, A1, A2, Wb);

    gemm_kernel<<<dim3(KP / 128, B_ / 128, 2), 256, 0, stream>>>(
        A1, A2, Wb, S1, S2, cs0pA, cs0pB, rowT1, rowT2);

    // sinkhorn: c1 in gemm; v0 -> (r1+c2) -> v2 -> (r2+c3) -> v3 -> (r3+cross)
    reducev_kernel<<<dim3(KP / 256, 1, 2), 256, 0, stream>>>(cs0pA, cs0pB, 32, v0A, v0B);
    rowcol_kernel<<<dim3(B_ / 8, 1, 2), 512, 0, stream>>>(S1, S2, v0A, v0B, partA, partB);
    reducev_kernel<<<dim3(KP / 256, 1, 2), 256, 0, stream>>>(partA, partB, 512, v2A, v2B);
    rowcol_kernel<<<dim3(B_ / 8, 1, 2), 512, 0, stream>>>(S1, S2, v2A, v2B, partA, partB);
    reducev_kernel<<<dim3(KP / 256, 1, 2), 256, 0, stream>>>(partA, partB, 512, v3A, v3B);

    rowcross_kernel<<<dim3(B_ / 4, 1, 1), 256, 0, stream>>>(S1, S2, v3A, v3B, cross);
    finisher_kernel<<<1, 256, 0, stream>>>(rowT1, rowT2, cross, out);
}

// Round 11
// 254.299 us; speedup vs baseline: 1.8562x; 1.2965x over previous
//
#include <hip/hip_runtime.h>

typedef unsigned short u16;
typedef unsigned int   u32;
typedef __attribute__((ext_vector_type(4))) float  f32x4;
typedef __attribute__((ext_vector_type(8))) __bf16 bf16x8;

#define B_    4096
#define D_    1024
#define K_    3000
#define KP    3072
#define INV_T 10.0f
#define INV_E 20.0f
#define NPART 512   // rowcol partial slices per matrix (one per block)

__device__ __forceinline__ u16 f2bf(float f) {  // round-to-nearest-even
    u32 u = __float_as_uint(f);
    u32 r = (u + 0x7fffu + ((u >> 16) & 1u)) >> 16;
    return (u16)r;
}
__device__ __forceinline__ void unpack8(uint4 v, float f[8]) {
    f[0] = __uint_as_float(v.x << 16); f[1] = __uint_as_float(v.x & 0xffff0000u);
    f[2] = __uint_as_float(v.y << 16); f[3] = __uint_as_float(v.y & 0xffff0000u);
    f[4] = __uint_as_float(v.z << 16); f[5] = __uint_as_float(v.z & 0xffff0000u);
    f[6] = __uint_as_float(v.w << 16); f[7] = __uint_as_float(v.w & 0xffff0000u);
}

#define GLDS(g, l) __builtin_amdgcn_global_load_lds( \
    (const __attribute__((address_space(1))) void*)(g), \
    (__attribute__((address_space(3))) void*)(l), 16, 0, 0)

// ---------------------------------------------------------------------------
// f32 -> bf16 conversion; W padded to KP rows with zeros.
// ---------------------------------------------------------------------------
__global__ __launch_bounds__(256) void convert_kernel(
    const float* __restrict__ z1, const float* __restrict__ z2,
    const float* __restrict__ W,
    u16* __restrict__ A1, u16* __restrict__ A2, u16* __restrict__ Wb)
{
    const int idx = blockIdx.x * 256 + threadIdx.x;
    const int n1 = B_ * D_ / 4;
    const int nW = KP * D_ / 4;
    ushort4 o;
    if (idx < n1) {
        float4 v = ((const float4*)z1)[idx];
        o.x = f2bf(v.x); o.y = f2bf(v.y); o.z = f2bf(v.z); o.w = f2bf(v.w);
        ((ushort4*)A1)[idx] = o;
    } else if (idx < 2 * n1) {
        const int j = idx - n1;
        float4 v = ((const float4*)z2)[j];
        o.x = f2bf(v.x); o.y = f2bf(v.y); o.z = f2bf(v.z); o.w = f2bf(v.w);
        ((ushort4*)A2)[j] = o;
    } else {
        const int j = idx - 2 * n1;
        if (j < nW) {
            const int row = j >> 8;
            if (row < K_) {
                float4 v = ((const float4*)W)[j];
                o.x = f2bf(v.x); o.y = f2bf(v.y); o.z = f2bf(v.z); o.w = f2bf(v.w);
            } else {
                o.x = 0; o.y = 0; o.z = 0; o.w = 0;
            }
            ((ushort4*)Wb)[j] = o;
        }
    }
}

// ---------------------------------------------------------------------------
// scores = z @ W^T. 128x128 tile, BK=64, 4 waves (2x2), 4x4 16x16x32 frags.
// LDS XOR-swizzle: 0 bank conflicts (verified round 3).
// Fused epilogue: bf16 score store, cs0 partial (col sums, u=1) as PLAIN
// stores into cs0part[bm][KP] slice, rowT (lse) via global atomics.
// ---------------------------------------------------------------------------
__global__ __launch_bounds__(256) void gemm_kernel(
    const u16* __restrict__ A1, const u16* __restrict__ A2,
    const u16* __restrict__ Wb,
    u16* __restrict__ S1, u16* __restrict__ S2,
    float* __restrict__ cs0pA, float* __restrict__ cs0pB,
    float* __restrict__ rowT1, float* __restrict__ rowT2)
{
    const int mat = blockIdx.z;
    const u16* A  = mat ? A2 : A1;
    u16* S        = mat ? S2 : S1;
    float* rowT   = mat ? rowT2 : rowT1;
    const int bm = blockIdx.y, bn = blockIdx.x;
    float* cs0p   = (mat ? cs0pB : cs0pA) + (size_t)bm * KP;

    __shared__ u16 At[128 * 64];
    __shared__ u16 Bt[128 * 64];
    __shared__ float sCol[128];
    __shared__ float sRow[128];

    const int tid  = threadIdx.x;
    const int wid  = tid >> 6, lane = tid & 63;
    const int wr   = wid >> 1, wc = wid & 1;

    f32x4 acc[4][4];
#pragma unroll
    for (int m = 0; m < 4; ++m)
#pragma unroll
        for (int n = 0; n < 4; ++n) {
            f32x4 z = {0.f, 0.f, 0.f, 0.f};
            acc[m][n] = z;
        }

    const int srow  = tid >> 3;                   // 0..31
    const int sslot = (tid & 7) ^ (srow & 7);     // swizzled source 16B slot
    const u16* Aga[4]; const u16* Bga[4]; u16* Ald[4]; u16* Bld[4];
#pragma unroll
    for (int r = 0; r < 4; ++r) {
        Aga[r] = A  + (size_t)(bm * 128 + r * 32 + srow) * D_ + sslot * 8;
        Bga[r] = Wb + (size_t)(bn * 128 + r * 32 + srow) * D_ + sslot * 8;
        Ald[r] = At + (r * 32 + srow) * 64 + (tid & 7) * 8;
        Bld[r] = Bt + (r * 32 + srow) * 64 + (tid & 7) * 8;
    }

    const int r15 = lane & 15, g = lane >> 4;
    const int sw0 = (g ^ (r15 & 7)) * 8;
    const int sw1 = ((g ^ (r15 & 7)) ^ 4) * 8;
    const u16* arow = At + (wr * 64 + r15) * 64;
    const u16* brow = Bt + (wc * 64 + r15) * 64;

    for (int kt = 0; kt < D_ / 64; ++kt) {
        const int ko = kt * 64;
#pragma unroll
        for (int r = 0; r < 4; ++r) {
            GLDS(Aga[r] + ko, Ald[r]);
            GLDS(Bga[r] + ko, Bld[r]);
        }
        __syncthreads();

        bf16x8 a[4], b[4];
#pragma unroll
        for (int m = 0; m < 4; ++m) a[m] = *reinterpret_cast<const bf16x8*>(arow + m * 16 * 64 + sw0);
#pragma unroll
        for (int n = 0; n < 4; ++n) b[n] = *reinterpret_cast<const bf16x8*>(brow + n * 16 * 64 + sw0);
#pragma unroll
        for (int m = 0; m < 4; ++m)
#pragma unroll
            for (int n = 0; n < 4; ++n)
                acc[m][n] = __builtin_amdgcn_mfma_f32_16x16x32_bf16(a[m], b[n], acc[m][n], 0, 0, 0);
#pragma unroll
        for (int m = 0; m < 4; ++m) a[m] = *reinterpret_cast<const bf16x8*>(arow + m * 16 * 64 + sw1);
#pragma unroll
        for (int n = 0; n < 4; ++n) b[n] = *reinterpret_cast<const bf16x8*>(brow + n * 16 * 64 + sw1);
#pragma unroll
        for (int m = 0; m < 4; ++m)
#pragma unroll
            for (int n = 0; n < 4; ++n)
                acc[m][n] = __builtin_amdgcn_mfma_f32_16x16x32_bf16(a[m], b[n], acc[m][n], 0, 0, 0);
        __syncthreads();
    }

    // ---- store scores as bf16 (C/D map: col=lane&15, row=(lane>>4)*4+r) ----
    const int lrow = wr * 64 + (lane >> 4) * 4;
    const int lcol = wc * 64 + (lane & 15);
#pragma unroll
    for (int m = 0; m < 4; ++m)
#pragma unroll
        for (int r = 0; r < 4; ++r) {
            u16* sp = S + (size_t)(bm * 128 + lrow + m * 16 + r) * KP + bn * 128 + lcol;
#pragma unroll
            for (int n = 0; n < 4; ++n) sp[n * 16] = f2bf(acc[m][n][r]);
        }

    // ---- fused reductions ----
    if (tid < 128) { sCol[tid] = 0.f; sRow[tid] = 0.f; }
    __syncthreads();

#pragma unroll
    for (int n = 0; n < 4; ++n) {
        float cs = 0.f;
#pragma unroll
        for (int m = 0; m < 4; ++m)
#pragma unroll
            for (int r = 0; r < 4; ++r) cs += __expf(acc[m][n][r] * INV_E);
        atomicAdd(&sCol[wc * 64 + n * 16 + (lane & 15)], cs);
    }

    const int gcol0 = bn * 128 + wc * 64 + (lane & 15);
#pragma unroll
    for (int m = 0; m < 4; ++m)
#pragma unroll
        for (int r = 0; r < 4; ++r) {
            float rs = 0.f;
#pragma unroll
            for (int n = 0; n < 4; ++n)
                if (gcol0 + n * 16 < K_) rs += __expf(acc[m][n][r] * INV_T);
            rs += __shfl_xor(rs, 1); rs += __shfl_xor(rs, 2);
            rs += __shfl_xor(rs, 4); rs += __shfl_xor(rs, 8);
            if ((lane & 15) == 0)
                atomicAdd(&sRow[wr * 64 + m * 16 + (lane >> 4) * 4 + r], rs);
        }
    __syncthreads();
    if (tid < 128) {
        cs0p[bn * 128 + tid] = sCol[tid];                 // plain partial store
        atomicAdd(&rowT[bm * 128 + tid], sRow[tid]);
    }
}

// ---------------------------------------------------------------------------
// reducev v2: v[j] = 1/(K * sum_p part[p][j]).  512 threads = 8 waves; block
// covers 64 columns; wave w sums slice-chunk w (P/8 slices); LDS tree-combine.
// Grid (KP/64, 1, 2) = 96 blocks (was 24 -> latency-bound, ~30us each).
// ---------------------------------------------------------------------------
__global__ __launch_bounds__(512) void reducev_kernel(
    const float* __restrict__ partA, const float* __restrict__ partB, int P,
    float* __restrict__ voutA, float* __restrict__ voutB)
{
    const int mat = blockIdx.z;
    const float* part = mat ? partB : partA;
    float* vout       = mat ? voutB : voutA;

    const int lane  = threadIdx.x & 63;
    const int chunk = threadIdx.x >> 6;          // 0..7
    const int col   = blockIdx.x * 64 + lane;
    const int cp    = P >> 3;                    // slices per chunk (4 or 64)

    const float* base = part + (size_t)(chunk * cp) * KP + col;
    float a0 = 0.f, a1 = 0.f, a2 = 0.f, a3 = 0.f;
    int p = 0;
    for (; p + 4 <= cp; p += 4) {
        a0 += base[(size_t)p * KP];
        a1 += base[(size_t)(p + 1) * KP];
        a2 += base[(size_t)(p + 2) * KP];
        a3 += base[(size_t)(p + 3) * KP];
    }
    for (; p < cp; ++p) a0 += base[(size_t)p * KP];

    __shared__ float red[8][64];
    red[chunk][lane] = (a0 + a1) + (a2 + a3);
    __syncthreads();
    if (threadIdx.x < 64) {
        const float t = ((red[0][lane] + red[1][lane]) + (red[2][lane] + red[3][lane]))
                      + ((red[4][lane] + red[5][lane]) + (red[6][lane] + red[7][lane]));
        vout[col] = __builtin_amdgcn_rcpf(3000.f * t);
    }
}

// ---------------------------------------------------------------------------
// FUSED row+col sinkhorn sweep, full occupancy, zero atomics:
//  Phase A: wave w (of 8) computes u for row bx*8+w: u = 1/(B*sum_j E_ij v_j)
//  Phase B: threads 0..374 each own 8 cols; accumulate E_ij*u_i over the 8
//           L2-hot rows in registers; plain float4 store to part[bx][cols].
// ---------------------------------------------------------------------------
__global__ __launch_bounds__(512) void rowcol_kernel(
    const u16* __restrict__ S1, const u16* __restrict__ S2,
    const float* __restrict__ vinA, const float* __restrict__ vinB,
    float* __restrict__ partA, float* __restrict__ partB)
{
    const int mat = blockIdx.z;
    const u16* S     = mat ? S2 : S1;
    const float* vin = mat ? vinB : vinA;
    float* part      = (mat ? partB : partA) + (size_t)blockIdx.x * KP;

    __shared__ float su[8];
    const int tid = threadIdx.x, wid = tid >> 6, lane = tid & 63;

    // ---- Phase A ----
    const int row = blockIdx.x * 8 + wid;
    const uint4*  sr = (const uint4*)(S + (size_t)row * KP);
    const float4* vv = (const float4*)vin;
    float acc = 0.f;
#pragma unroll
    for (int k = 0; k < 6; ++k) {
        const int c = lane + k * 64;
        if (k == 5 && c >= K_ / 8) continue;
        uint4 v = sr[c];
        float4 w0 = vv[2 * c], w1 = vv[2 * c + 1];
        float f[8]; unpack8(v, f);
        acc += __expf(f[0] * INV_E) * w0.x;
        acc += __expf(f[1] * INV_E) * w0.y;
        acc += __expf(f[2] * INV_E) * w0.z;
        acc += __expf(f[3] * INV_E) * w0.w;
        acc += __expf(f[4] * INV_E) * w1.x;
        acc += __expf(f[5] * INV_E) * w1.y;
        acc += __expf(f[6] * INV_E) * w1.z;
        acc += __expf(f[7] * INV_E) * w1.w;
    }
#pragma unroll
    for (int m = 1; m < 64; m <<= 1) acc += __shfl_xor(acc, m);
    if (lane == 0) su[wid] = 1.f / (4096.f * acc);
    __syncthreads();

    // ---- Phase B ----
    if (tid < K_ / 8) {
        const int c0 = tid * 8;
        float p[8] = {0.f, 0.f, 0.f, 0.f, 0.f, 0.f, 0.f, 0.f};
        const u16* Sb = S + (size_t)(blockIdx.x * 8) * KP;
#pragma unroll
        for (int r = 0; r < 8; ++r) {
            const float ui = su[r];
            uint4 v = *(const uint4*)(Sb + (size_t)r * KP + c0);
            float f[8]; unpack8(v, f);
#pragma unroll
            for (int e = 0; e < 8; ++e) p[e] += __expf(f[e] * INV_E) * ui;
        }
        float4* op = (float4*)(part + c0);
        op[0] = make_float4(p[0], p[1], p[2], p[3]);
        op[1] = make_float4(p[4], p[5], p[6], p[7]);
    }
}

// ---------------------------------------------------------------------------
// fused row3 + cross pass. Per row i (wave-per-row), with precomputed v:
//   t1 = sum_j E1*v1,  d1 = sum_j E1*v1*s2;  t2, d2 symmetric.
// cross[0] += d2/(B*t2); cross[1] += d1/(B*t1)
// ---------------------------------------------------------------------------
__global__ __launch_bounds__(256) void rowcross_kernel(
    const u16* __restrict__ S1, const u16* __restrict__ S2,
    const float* __restrict__ v3_1, const float* __restrict__ v3_2,
    float* __restrict__ cross)
{
    const int wid  = threadIdx.x >> 6, lane = threadIdx.x & 63;
    const int row  = blockIdx.x * 4 + wid;
    const uint4*  s1r = (const uint4*)(S1 + (size_t)row * KP);
    const uint4*  s2r = (const uint4*)(S2 + (size_t)row * KP);
    const float4* v1v = (const float4*)v3_1;
    const float4* v2v = (const float4*)v3_2;

    float t1 = 0.f, d1 = 0.f, t2 = 0.f, d2 = 0.f;
#pragma unroll
    for (int k = 0; k < 6; ++k) {
        const int c = lane + k * 64;
        if (k == 5 && c >= K_ / 8) break;
        uint4 va = s1r[c], vb = s2r[c];
        float4 x0 = v1v[2 * c], x1 = v1v[2 * c + 1];
        float4 y0 = v2v[2 * c], y1 = v2v[2 * c + 1];
        float f1[8], f2[8]; unpack8(va, f1); unpack8(vb, f2);
        const float w1[8] = {x0.x, x0.y, x0.z, x0.w, x1.x, x1.y, x1.z, x1.w};
        const float w2[8] = {y0.x, y0.y, y0.z, y0.w, y1.x, y1.y, y1.z, y1.w};
#pragma unroll
        for (int e = 0; e < 8; ++e) {
            const float e1 = __expf(f1[e] * INV_E) * w1[e];
            const float e2 = __expf(f2[e] * INV_E) * w2[e];
            t1 += e1; d1 += e1 * f2[e];
            t2 += e2; d2 += e2 * f1[e];
        }
    }
#pragma unroll
    for (int m = 1; m < 64; m <<= 1) {
        t1 += __shfl_xor(t1, m); d1 += __shfl_xor(d1, m);
        t2 += __shfl_xor(t2, m); d2 += __shfl_xor(d2, m);
    }
    __shared__ float sa[4], sb[4];
    if (lane == 0) {
        sa[wid] = d2 / (4096.f * t2);
        sb[wid] = d1 / (4096.f * t1);
    }
    __syncthreads();
    if (threadIdx.x == 0) {
        atomicAdd(&cross[0], sa[0] + sa[1] + sa[2] + sa[3]);
        atomicAdd(&cross[1], sb[0] + sb[1] + sb[2] + sb[3]);
    }
}

// ---------------------------------------------------------------------------
// finisher: loss = -0.5*[ (cross1+cross2)/(B*T) - (sum lse1 + sum lse2)/B^2 ]
// ---------------------------------------------------------------------------
__global__ __launch_bounds__(256) void finisher_kernel(
    const float* __restrict__ rowT1, const float* __restrict__ rowT2,
    const float* __restrict__ cross, float* __restrict__ out)
{
    float l = 0.f;
    for (int i = threadIdx.x; i < B_; i += 256)
        l += logf(rowT1[i]) + logf(rowT2[i]);
#pragma unroll
    for (int m = 1; m < 64; m <<= 1) l += __shfl_xor(l, m);
    __shared__ float s[4];
    if ((threadIdx.x & 63) == 0) s[threadIdx.x >> 6] = l;
    __syncthreads();
    if (threadIdx.x == 0) {
        const float sumlse = s[0] + s[1] + s[2] + s[3];
        const float t = (cross[0] + cross[1]) * (1.0f / (4096.0f * 0.1f));
        const float term = t - sumlse * (1.0f / (4096.0f * 4096.0f));
        out[0] = -0.5f * term;
    }
}

// ---------------------------------------------------------------------------
extern "C" void kernel_launch(void* const* d_in, const int* in_sizes, int n_in,
                              void* d_out, int out_size, void* d_ws, size_t ws_size,
                              hipStream_t stream)
{
    const float* z1 = (const float*)d_in[0];
    const float* z2 = (const float*)d_in[1];
    const float* W  = (const float*)d_in[2];
    float* out = (float*)d_out;

    char* p = (char*)d_ws;
    u16* A1 = (u16*)p; p += (size_t)B_ * D_ * 2;
    u16* A2 = (u16*)p; p += (size_t)B_ * D_ * 2;
    u16* Wb = (u16*)p; p += (size_t)KP * D_ * 2;
    u16* S1 = (u16*)p; p += (size_t)B_ * KP * 2;
    u16* S2 = (u16*)p; p += (size_t)B_ * KP * 2;
    float* cs0pA = (float*)p; p += (size_t)32 * KP * 4;       // gemm partials
    float* cs0pB = (float*)p; p += (size_t)32 * KP * 4;
    float* partA = (float*)p; p += (size_t)NPART * KP * 4;    // rowcol partials
    float* partB = (float*)p; p += (size_t)NPART * KP * 4;
    float* v0A = (float*)p; p += KP * 4;
    float* v0B = (float*)p; p += KP * 4;
    float* v2A = (float*)p; p += KP * 4;
    float* v2B = (float*)p; p += KP * 4;
    float* v3A = (float*)p; p += KP * 4;
    float* v3B = (float*)p; p += KP * 4;
    float* rowT1 = (float*)p; p += B_ * 4;   // atomic accumulators (zeroed)
    float* rowT2 = (float*)p; p += B_ * 4;
    float* cross = (float*)p; p += 16 * 4;

    // zero only the atomic accumulators: rowT1, rowT2, cross (contiguous)
    hipMemsetAsync(rowT1, 0, 2 * B_ * 4 + 16 * 4, stream);

    convert_kernel<<<11264, 256, 0, stream>>>(z1, z2, W, A1, A2, Wb);

    gemm_kernel<<<dim3(KP / 128, B_ / 128, 2), 256, 0, stream>>>(
        A1, A2, Wb, S1, S2, cs0pA, cs0pB, rowT1, rowT2);

    // sinkhorn: c1 in gemm; v0 -> (r1+c2) -> v2 -> (r2+c3) -> v3 -> (r3+cross)
    reducev_kernel<<<dim3(KP / 64, 1, 2), 512, 0, stream>>>(cs0pA, cs0pB, 32, v0A, v0B);
    rowcol_kernel<<<dim3(B_ / 8, 1, 2), 512, 0, stream>>>(S1, S2, v0A, v0B, partA, partB);
    reducev_kernel<<<dim3(KP / 64, 1, 2), 512, 0, stream>>>(partA, partB, 512, v2A, v2B);
    rowcol_kernel<<<dim3(B_ / 8, 1, 2), 512, 0, stream>>>(S1, S2, v2A, v2B, partA, partB);
    reducev_kernel<<<dim3(KP / 64, 1, 2), 512, 0, stream>>>(partA, partB, 512, v3A, v3B);

    rowcross_kernel<<<dim3(B_ / 4, 1, 1), 256, 0, stream>>>(S1, S2, v3A, v3B, cross);
    finisher_kernel<<<1, 256, 0, stream>>>(rowT1, rowT2, cross, out);
}